// Round 1
// baseline (169.893 us; speedup 1.0000x reference)
//
#include <hip/hip_runtime.h>

namespace {
constexpr int BATCH = 32;
constexpr int H = 192;
constexpr int W = 192;
constexpr int HW = H * W;          // 36864
constexpr int NCLS = 25;
constexpr int LUT = 26 * 25;       // transposed LUT: Kt[idx][lab], 26th col = 0 sentinel

constexpr int OFF_PRED   = 0;
constexpr int OFF_MASKF  = BATCH * 3 * HW;                  // 3,538,944
constexpr int OFF_OMAF   = OFF_MASKF + BATCH * NCLS * HW;   // 33,030,144
constexpr int OFF_ATTN   = OFF_OMAF + BATCH * HW;           // 34,209,792
constexpr int OFF_MASKB  = OFF_ATTN + BATCH * HW;           // 35,389,440
constexpr int OFF_OMAB   = OFF_MASKB + BATCH * NCLS * HW;   // 64,880,640
constexpr int OFF_OMATTN = OFF_OMAB + BATCH * HW;           // 66,060,288

constexpr int NTHREADS = BATCH * H * (W / 4);               // 294,912
}  // namespace

// ---------------------------------------------------------------------------
// Kernel 1: one-hot mask writes (the 236 MB that dominate) + seg/appear/attn.
// One thread handles 4 consecutive x pixels (float4 stores).
// ---------------------------------------------------------------------------
__global__ __launch_bounds__(256) void k_mask_seg(
    const int* __restrict__ labF, const int* __restrict__ labB,
    const float* __restrict__ mk, float* __restrict__ out)
{
    __shared__ float sk[LUT];
    for (int i = threadIdx.x; i < LUT; i += 256) {
        const int idx = i / 26;
        const int l = i - idx * 26;
        sk[i] = (l < NCLS) ? mk[l * 25 + idx] : 0.0f;  // Kt[idx*26 + lab]
    }
    __syncthreads();

    const int t = blockIdx.x * 256 + threadIdx.x;   // grid is exact
    const int x4 = t % 48;
    const int rest = t / 48;
    const int y = rest % H;
    const int b = rest / H;
    const int x = x4 * 4;
    const int pix = b * HW + y * W + x;

    const int4 lf = *reinterpret_cast<const int4*>(labF + pix);
    const int4 lb = *reinterpret_cast<const int4*>(labB + pix);

    // --- one-hot mask planes (coalesced float4 per plane) ---
    {
        float4* __restrict__ mf =
            reinterpret_cast<float4*>(out + OFF_MASKF + b * (NCLS * HW) + y * W + x);
        float4* __restrict__ mb =
            reinterpret_cast<float4*>(out + OFF_MASKB + b * (NCLS * HW) + y * W + x);
#pragma unroll
        for (int k = 0; k < NCLS; ++k) {
            mf[k * (HW / 4)] = make_float4(lf.x == k ? 1.f : 0.f, lf.y == k ? 1.f : 0.f,
                                           lf.z == k ? 1.f : 0.f, lf.w == k ? 1.f : 0.f);
            mb[k * (HW / 4)] = make_float4(lb.x == k ? 1.f : 0.f, lb.y == k ? 1.f : 0.f,
                                           lb.z == k ? 1.f : 0.f, lb.w == k ? 1.f : 0.f);
        }
    }

    // --- seg via 5x5 label-gather through the LUT ---
    float segf[4] = {0.f, 0.f, 0.f, 0.f};
    float segb[4] = {0.f, 0.f, 0.f, 0.f};
#pragma unroll
    for (int dy = 0; dy < 5; ++dy) {
        const int yy = y + dy - 2;
        if (yy < 0 || yy >= H) continue;
        const int rowo = b * HW + yy * W;
        int ljf[8], ljb[8];
#pragma unroll
        for (int j = 0; j < 8; ++j) {
            const int xx = x - 2 + j;
            const bool v = (xx >= 0) & (xx < W);
            ljf[j] = v ? labF[rowo + xx] : NCLS;   // sentinel -> 0 weight
            ljb[j] = v ? labB[rowo + xx] : NCLS;
        }
#pragma unroll
        for (int dx = 0; dx < 5; ++dx) {
            const int base = (dy * 5 + dx) * 26;
#pragma unroll
            for (int i = 0; i < 4; ++i) {
                segf[i] += sk[base + ljf[i + dx]];
                segb[i] += sk[base + ljb[i + dx]];
            }
        }
    }

    float v_omaf[4], v_omab[4], v_at[4], v_omat[4];
#pragma unroll
    for (int i = 0; i < 4; ++i) {
        const float af = fmaxf(1.f - fmaxf(segf[i] - 1.f, 0.f), 0.f);  // appear_f
        const float ab = fmaxf(1.f - fmaxf(segb[i] - 1.f, 0.f), 0.f);
        const float scf = 1.f - fmaxf(1.f - segf[i], 0.f);             // clamped seg
        const float scb = 1.f - fmaxf(1.f - segb[i], 0.f);
        const float at = (scf + 1e-5f) / (scf + scb + 2e-5f);
        v_omaf[i] = 1.f - af;
        v_omab[i] = 1.f - ab;
        v_at[i]   = at;
        v_omat[i] = 1.f - at;
    }
    *reinterpret_cast<float4*>(out + OFF_OMAF + pix) =
        make_float4(v_omaf[0], v_omaf[1], v_omaf[2], v_omaf[3]);
    *reinterpret_cast<float4*>(out + OFF_OMAB + pix) =
        make_float4(v_omab[0], v_omab[1], v_omab[2], v_omab[3]);
    *reinterpret_cast<float4*>(out + OFF_ATTN + pix) =
        make_float4(v_at[0], v_at[1], v_at[2], v_at[3]);
    *reinterpret_cast<float4*>(out + OFF_OMATTN + pix) =
        make_float4(v_omat[0], v_omat[1], v_omat[2], v_omat[3]);
}

// ---------------------------------------------------------------------------
// Kernel 2: pred = attn*pred_f + (1-attn)*pred_b, 5x5 weighted window.
// appear and attn are read back from d_out (written by kernel 1).
// ---------------------------------------------------------------------------
__device__ __forceinline__ void accum_img(
    const float* __restrict__ im, const int* __restrict__ lab,
    const float* __restrict__ omA, const float* sk,
    int b, int y, int x, float acc[3][4])
{
#pragma unroll
    for (int dy = 0; dy < 5; ++dy) {
        const int yy = y + dy - 2;
        if (yy < 0 || yy >= H) continue;
        const int rowo = b * HW + yy * W;
        const int imo = b * (6 * HW) + 3 * HW + yy * W;  // channels 3..5
        float a[8], iv0[8], iv1[8], iv2[8];
        int l[8];
#pragma unroll
        for (int j = 0; j < 8; ++j) {
            const int xx = x - 2 + j;
            const bool v = (xx >= 0) & (xx < W);
            if (v) {
                l[j]  = lab[rowo + xx];
                a[j]  = 1.f - omA[rowo + xx];
                iv0[j] = im[imo + xx];
                iv1[j] = im[imo + HW + xx];
                iv2[j] = im[imo + 2 * HW + xx];
            } else {
                l[j] = NCLS; a[j] = 0.f; iv0[j] = 0.f; iv1[j] = 0.f; iv2[j] = 0.f;
            }
        }
#pragma unroll
        for (int dx = 0; dx < 5; ++dx) {
            const int base = (dy * 5 + dx) * 26;
#pragma unroll
            for (int i = 0; i < 4; ++i) {
                const int j = i + dx;
                const float w = a[j] * sk[base + l[j]];
                acc[0][i] = fmaf(w, iv0[j], acc[0][i]);
                acc[1][i] = fmaf(w, iv1[j], acc[1][i]);
                acc[2][i] = fmaf(w, iv2[j], acc[2][i]);
            }
        }
    }
}

__global__ __launch_bounds__(256) void k_pred(
    const float* __restrict__ imF, const float* __restrict__ imB,
    const int* __restrict__ labF, const int* __restrict__ labB,
    const float* __restrict__ mk, float* __restrict__ out)
{
    __shared__ float sk[LUT];
    for (int i = threadIdx.x; i < LUT; i += 256) {
        const int idx = i / 26;
        const int l = i - idx * 26;
        sk[i] = (l < NCLS) ? mk[l * 25 + idx] : 0.0f;
    }
    __syncthreads();

    const int t = blockIdx.x * 256 + threadIdx.x;
    const int x4 = t % 48;
    const int rest = t / 48;
    const int y = rest % H;
    const int b = rest / H;
    const int x = x4 * 4;
    const int pix = b * HW + y * W + x;

    float accf[3][4] = {};
    float accb[3][4] = {};
    accum_img(imF, labF, out + OFF_OMAF, sk, b, y, x, accf);
    accum_img(imB, labB, out + OFF_OMAB, sk, b, y, x, accb);

    const float4 at4 = *reinterpret_cast<const float4*>(out + OFF_ATTN + pix);
    const float atv[4] = {at4.x, at4.y, at4.z, at4.w};

    float* pout = out + OFF_PRED + b * (3 * HW) + y * W + x;
#pragma unroll
    for (int c = 0; c < 3; ++c) {
        float p[4];
#pragma unroll
        for (int i = 0; i < 4; ++i)
            p[i] = atv[i] * accf[c][i] + (1.f - atv[i]) * accb[c][i];
        *reinterpret_cast<float4*>(pout + c * HW) = make_float4(p[0], p[1], p[2], p[3]);
    }
}

extern "C" void kernel_launch(void* const* d_in, const int* in_sizes, int n_in,
                              void* d_out, int out_size, void* d_ws, size_t ws_size,
                              hipStream_t stream) {
    const float* imF  = (const float*)d_in[0];
    const float* imB  = (const float*)d_in[1];
    const int*   labF = (const int*)d_in[2];
    const int*   labB = (const int*)d_in[3];
    const float* mk   = (const float*)d_in[4];
    float* out = (float*)d_out;

    const int grid = NTHREADS / 256;  // 1152 blocks, exact
    k_mask_seg<<<grid, 256, 0, stream>>>(labF, labB, mk, out);
    k_pred<<<grid, 256, 0, stream>>>(imF, imB, labF, labB, mk, out);
}

// Round 3
// 87.707 us; speedup vs baseline: 1.9371x; 1.9371x over previous
//
#include <hip/hip_runtime.h>

typedef float f32x4 __attribute__((ext_vector_type(4)));

namespace {
constexpr int BATCH = 32;
constexpr int H = 192;
constexpr int W = 192;
constexpr int HW = H * W;          // 36864
constexpr int NCLS = 25;
constexpr int LUT = 26 * 25;       // transposed LUT: Kt[idx][lab], 26th col = 0 sentinel

constexpr int OFF_PRED   = 0;
constexpr int OFF_MASKF  = BATCH * 3 * HW;
constexpr int OFF_OMAF   = OFF_MASKF + BATCH * NCLS * HW;
constexpr int OFF_ATTN   = OFF_OMAF + BATCH * HW;
constexpr int OFF_MASKB  = OFF_ATTN + BATCH * HW;
constexpr int OFF_OMAB   = OFF_MASKB + BATCH * NCLS * HW;
constexpr int OFF_OMATTN = OFF_OMAB + BATCH * HW;

constexpr int NTHREADS = BATCH * H * (W / 4);   // 294,912 -> 1152 blocks of 256
}  // namespace

__device__ __forceinline__ void nt_store4(float* p, float a, float b, float c, float d) {
    f32x4 v = {a, b, c, d};
    __builtin_nontemporal_store(v, reinterpret_cast<f32x4*>(p));
}

// Load the 12-int label window [x-4, x+8) with 3 aligned int4 loads.
// Out-of-row entries get the sentinel NCLS (maps to 0 weight in the LUT).
__device__ __forceinline__ void lab_window(int lw[12], const int* __restrict__ row,
                                           int x, int x4) {
    if (x4 > 0) {
        const int4 a = *reinterpret_cast<const int4*>(row + x - 4);
        lw[0] = a.x; lw[1] = a.y; lw[2] = a.z; lw[3] = a.w;
    } else {
        lw[0] = NCLS; lw[1] = NCLS; lw[2] = NCLS; lw[3] = NCLS;
    }
    {
        const int4 c = *reinterpret_cast<const int4*>(row + x);
        lw[4] = c.x; lw[5] = c.y; lw[6] = c.z; lw[7] = c.w;
    }
    if (x4 < 47) {
        const int4 e = *reinterpret_cast<const int4*>(row + x + 4);
        lw[8] = e.x; lw[9] = e.y; lw[10] = e.z; lw[11] = e.w;
    } else {
        lw[8] = NCLS; lw[9] = NCLS; lw[10] = NCLS; lw[11] = NCLS;
    }
}

__device__ __forceinline__ void f4_window(float w[12], const float* __restrict__ row,
                                          int x, int x4, float edge) {
    if (x4 > 0) {
        const float4 a = *reinterpret_cast<const float4*>(row + x - 4);
        w[0] = a.x; w[1] = a.y; w[2] = a.z; w[3] = a.w;
    } else {
        w[0] = edge; w[1] = edge; w[2] = edge; w[3] = edge;
    }
    {
        const float4 c = *reinterpret_cast<const float4*>(row + x);
        w[4] = c.x; w[5] = c.y; w[6] = c.z; w[7] = c.w;
    }
    if (x4 < 47) {
        const float4 e = *reinterpret_cast<const float4*>(row + x + 4);
        w[8] = e.x; w[9] = e.y; w[10] = e.z; w[11] = e.w;
    } else {
        w[8] = edge; w[9] = edge; w[10] = edge; w[11] = edge;
    }
}

// ---------------------------------------------------------------------------
// Kernel 1: one-hot masks (nontemporal stream) + seg/appear/attn.
// ---------------------------------------------------------------------------
__global__ __launch_bounds__(256) void k_mask_seg(
    const int* __restrict__ labF, const int* __restrict__ labB,
    const float* __restrict__ mk, float* __restrict__ out)
{
    __shared__ float sk[LUT];
    for (int i = threadIdx.x; i < LUT; i += 256) {
        const int idx = i / 26;
        const int l = i - idx * 26;
        sk[i] = (l < NCLS) ? mk[l * 25 + idx] : 0.0f;  // Kt[idx*26 + lab]
    }
    __syncthreads();

    const int t = blockIdx.x * 256 + threadIdx.x;
    const int x4 = t % 48;
    const int rest = t / 48;
    const int y = rest % H;
    const int b = rest / H;
    const int x = x4 * 4;
    const int pix = b * HW + y * W + x;

    const int4 lf = *reinterpret_cast<const int4*>(labF + pix);
    const int4 lb = *reinterpret_cast<const int4*>(labB + pix);

    // --- one-hot mask planes: write-once stream, bypass L2 ---
    {
        float* __restrict__ mf = out + OFF_MASKF + b * (NCLS * HW) + y * W + x;
        float* __restrict__ mb = out + OFF_MASKB + b * (NCLS * HW) + y * W + x;
#pragma unroll
        for (int k = 0; k < NCLS; ++k) {
            nt_store4(mf + k * HW, lf.x == k ? 1.f : 0.f, lf.y == k ? 1.f : 0.f,
                      lf.z == k ? 1.f : 0.f, lf.w == k ? 1.f : 0.f);
            nt_store4(mb + k * HW, lb.x == k ? 1.f : 0.f, lb.y == k ? 1.f : 0.f,
                      lb.z == k ? 1.f : 0.f, lb.w == k ? 1.f : 0.f);
        }
    }

    // --- seg via 5x5 label-gather through the LUT (vector window loads) ---
    float segf[4] = {0.f, 0.f, 0.f, 0.f};
    float segb[4] = {0.f, 0.f, 0.f, 0.f};
#pragma unroll
    for (int dy = 0; dy < 5; ++dy) {
        const int yy = y + dy - 2;
        if (yy < 0 || yy >= H) continue;
        int lwF[12], lwB[12];
        lab_window(lwF, labF + b * HW + yy * W, x, x4);
        lab_window(lwB, labB + b * HW + yy * W, x, x4);
#pragma unroll
        for (int dx = 0; dx < 5; ++dx) {
            const int base = (dy * 5 + dx) * 26;
#pragma unroll
            for (int i = 0; i < 4; ++i) {
                segf[i] += sk[base + lwF[i + dx + 2]];
                segb[i] += sk[base + lwB[i + dx + 2]];
            }
        }
    }

    float v_omaf[4], v_omab[4], v_at[4], v_omat[4];
#pragma unroll
    for (int i = 0; i < 4; ++i) {
        const float af = fmaxf(1.f - fmaxf(segf[i] - 1.f, 0.f), 0.f);
        const float ab = fmaxf(1.f - fmaxf(segb[i] - 1.f, 0.f), 0.f);
        const float scf = 1.f - fmaxf(1.f - segf[i], 0.f);
        const float scb = 1.f - fmaxf(1.f - segb[i], 0.f);
        const float at = (scf + 1e-5f) / (scf + scb + 2e-5f);
        v_omaf[i] = 1.f - af;
        v_omab[i] = 1.f - ab;
        v_at[i]   = at;
        v_omat[i] = 1.f - at;
    }
    // omaf/omab/attn are re-read by kernel 2 -> normal stores (stay in L2).
    *reinterpret_cast<float4*>(out + OFF_OMAF + pix) =
        make_float4(v_omaf[0], v_omaf[1], v_omaf[2], v_omaf[3]);
    *reinterpret_cast<float4*>(out + OFF_OMAB + pix) =
        make_float4(v_omab[0], v_omab[1], v_omab[2], v_omab[3]);
    *reinterpret_cast<float4*>(out + OFF_ATTN + pix) =
        make_float4(v_at[0], v_at[1], v_at[2], v_at[3]);
    nt_store4(out + OFF_OMATTN + pix, v_omat[0], v_omat[1], v_omat[2], v_omat[3]);
}

// ---------------------------------------------------------------------------
// Kernel 2: pred = attn*pred_f + (1-attn)*pred_b (vector window loads).
// ---------------------------------------------------------------------------
__device__ __forceinline__ void accum_img(
    const float* __restrict__ im, const int* __restrict__ lab,
    const float* __restrict__ omA, const float* sk,
    int b, int y, int x, int x4, float acc[3][4])
{
#pragma unroll
    for (int dy = 0; dy < 5; ++dy) {
        const int yy = y + dy - 2;
        if (yy < 0 || yy >= H) continue;
        const int rowo = b * HW + yy * W;
        const int imo = b * (6 * HW) + 3 * HW + yy * W;  // channels 3..5

        int lw[12];
        lab_window(lw, lab + rowo, x, x4);
        float aw[12], v0[12], v1[12], v2[12];
        f4_window(aw, omA + rowo, x, x4, 1.f);   // edge: om=1 -> a=0
        f4_window(v0, im + imo, x, x4, 0.f);
        f4_window(v1, im + imo + HW, x, x4, 0.f);
        f4_window(v2, im + imo + 2 * HW, x, x4, 0.f);
        float a[12];
#pragma unroll
        for (int j = 0; j < 12; ++j) a[j] = 1.f - aw[j];

#pragma unroll
        for (int dx = 0; dx < 5; ++dx) {
            const int base = (dy * 5 + dx) * 26;
#pragma unroll
            for (int i = 0; i < 4; ++i) {
                const int li = i + dx + 2;
                const float w = a[li] * sk[base + lw[li]];
                acc[0][i] = fmaf(w, v0[li], acc[0][i]);
                acc[1][i] = fmaf(w, v1[li], acc[1][i]);
                acc[2][i] = fmaf(w, v2[li], acc[2][i]);
            }
        }
    }
}

__global__ __launch_bounds__(256) void k_pred(
    const float* __restrict__ imF, const float* __restrict__ imB,
    const int* __restrict__ labF, const int* __restrict__ labB,
    const float* __restrict__ mk, float* __restrict__ out)
{
    __shared__ float sk[LUT];
    for (int i = threadIdx.x; i < LUT; i += 256) {
        const int idx = i / 26;
        const int l = i - idx * 26;
        sk[i] = (l < NCLS) ? mk[l * 25 + idx] : 0.0f;
    }
    __syncthreads();

    const int t = blockIdx.x * 256 + threadIdx.x;
    const int x4 = t % 48;
    const int rest = t / 48;
    const int y = rest % H;
    const int b = rest / H;
    const int x = x4 * 4;
    const int pix = b * HW + y * W + x;

    float accf[3][4] = {};
    float accb[3][4] = {};
    accum_img(imF, labF, out + OFF_OMAF, sk, b, y, x, x4, accf);
    accum_img(imB, labB, out + OFF_OMAB, sk, b, y, x, x4, accb);

    const float4 at4 = *reinterpret_cast<const float4*>(out + OFF_ATTN + pix);
    const float atv[4] = {at4.x, at4.y, at4.z, at4.w};

    float* pout = out + OFF_PRED + b * (3 * HW) + y * W + x;
#pragma unroll
    for (int c = 0; c < 3; ++c) {
        float p[4];
#pragma unroll
        for (int i = 0; i < 4; ++i)
            p[i] = atv[i] * accf[c][i] + (1.f - atv[i]) * accb[c][i];
        nt_store4(pout + c * HW, p[0], p[1], p[2], p[3]);
    }
}

extern "C" void kernel_launch(void* const* d_in, const int* in_sizes, int n_in,
                              void* d_out, int out_size, void* d_ws, size_t ws_size,
                              hipStream_t stream) {
    const float* imF  = (const float*)d_in[0];
    const float* imB  = (const float*)d_in[1];
    const int*   labF = (const int*)d_in[2];
    const int*   labB = (const int*)d_in[3];
    const float* mk   = (const float*)d_in[4];
    float* out = (float*)d_out;

    const int grid = NTHREADS / 256;  // 1152 blocks, exact
    k_mask_seg<<<grid, 256, 0, stream>>>(labF, labB, mk, out);
    k_pred<<<grid, 256, 0, stream>>>(imF, imB, labF, labB, mk, out);
}